// Round 14
// baseline (222.413 us; speedup 1.0000x reference)
//
#include <hip/hip_runtime.h>
#include <math.h>

// ---------------------------------------------------------------------------
// GaussianQuant — MFMA-filtered argmax, R14.
// score[n,k] = sum_d p*c + q*c^2;  u=[p,q], v=[c,c^2], score = u.v  (K=64)
// fp16 HI-ONLY approx: |err| <= 1.05e-3*S (rigorous), S = sum |p|M1+|q|M1^2.
// Filter: per (row, GROUP of 4 columns) approx top-1, with (tile<<2)|c16lo2
//   packed into the value's low 8 mantissa bits (2 and_or + 1 max3 / pair).
// Merge (two-phase, sound): A* = max group-max; Btot = 1.05e-3*S +
//   1e-4*(|A*|+1) + 1e-3  (covers fp16 approx + 8-bit pack + MFMA accum).
//   Phase A: exact-rescore stored winners of groups >= A* - 2*Btot -> E*.
//   Phase B: full rescan (256 k) of groups with W1 + Btot >= E*.
// R14: W1 shrunk 16->4 MB (groups of 4) in block-contiguous [split][row][4]
// layout (R13 had 77 MB HBM write amplification from scattered 64B chunks);
// gather split back out of merge for coalesced out0 writes.
// ---------------------------------------------------------------------------

typedef _Float16 half8 __attribute__((ext_vector_type(8)));
typedef float f32x4 __attribute__((ext_vector_type(4)));

#define DIM 32
#define NTOK 2048
#define NROWS 16384
#define KSIZE 16384
#define NSPLIT 16
#define SPLITK 1024
#define PMASK 0xFFFFFF00u              // clear low 8 mantissa bits (tile|c2)

// ws layout (bytes); [0,4096) zeroed by memset each launch
#define WS_M1   0                       // 32 float (atomicMax targets)
#define WS_KL   256                     // 1 double (atomicAdd target)
#define WS_PQ   4096                    // 4 MB fp32 [row][64]
#define WS_AH   (WS_PQ + 4194304)       // 2 MB fp16 [row][64]
#define WS_BH   (WS_AH + 2097152)       // 2 MB fp16 [k][64] PRE-SWIZZLED
#define WS_W1   (WS_BH + 2097152)       // 4 MB fp32 [split][row][4] packed
#define WS_IDX  (WS_W1 + 4194304)       // 64 KB int

// Fused prep, 1024 blocks: [0,512) pack codebook (swizzled) + per-dim max;
// [512,1024) compute p,q + fp16 pack + KL partial sum.
__global__ __launch_bounds__(256) void prep_kernel(const float* __restrict__ cb,
                                                   const float* __restrict__ z,
                                                   _Float16* __restrict__ Bh,
                                                   float* __restrict__ M1,
                                                   float* __restrict__ PQ,
                                                   _Float16* __restrict__ Ah,
                                                   double* __restrict__ klsum) {
  const int w = threadIdx.x >> 6, l = threadIdx.x & 63;
  const int sub = l >> 5, d = l & 31;
  if (blockIdx.x < 512) {
    __shared__ float lm[8][DIM];
    float m = 0.0f;
#pragma unroll
    for (int i = 0; i < 4; ++i) {
      const int k = blockIdx.x * 32 + i * 8 + w * 2 + sub;
      const float c = cb[k * DIM + d];
      // swizzled slot layout: logical slot s (8 halfs) stored at s ^ (k&7)
      const int key = k & 7;
      const int sc = (d >> 3) ^ key;          // c-part: logical slot d>>3
      const int sq = (4 + (d >> 3)) ^ key;    // c^2-part: logical slot 4+d>>3
      Bh[(size_t)k * 64 + sc * 8 + (d & 7)] = (_Float16)c;
      Bh[(size_t)k * 64 + sq * 8 + (d & 7)] = (_Float16)(c * c);
      m = fmaxf(m, fabsf(c));
    }
    lm[threadIdx.x >> 5][d] = m;
    __syncthreads();
    if (threadIdx.x < DIM) {
      float x = lm[0][threadIdx.x];
#pragma unroll
      for (int i = 1; i < 8; ++i) x = fmaxf(x, lm[i][threadIdx.x]);
      atomicMax((unsigned*)&M1[threadIdx.x], __float_as_uint(x));
    }
  } else {
    const int blk = blockIdx.x - 512;
    double kacc = 0.0;
#pragma unroll 1
    for (int i = 0; i < 4; ++i) {
      const int row = blk * 32 + i * 8 + w * 2 + sub;
      const int t = row >> 3, c = row & 7;
      const float mu = z[t * 512 + d * 8 + c];
      float lv = z[t * 512 + 256 + d * 8 + c];
      lv = fminf(fmaxf(lv, -30.0f), 20.0f);
      const float stdv = expf(0.5f * lv);
      const float iv = 1.0f / (stdv * stdv);   // identical to R2 expression
      const float p = mu * iv;
      const float q = 0.5f * (1.0f - iv);
      PQ[(size_t)row * 64 + d] = p;
      PQ[(size_t)row * 64 + 32 + d] = q;
      Ah[(size_t)row * 64 + d] = (_Float16)p;
      Ah[(size_t)row * 64 + 32 + d] = (_Float16)q;
      kacc += (double)(mu * mu + stdv * stdv - 1.0f - lv);
    }
#pragma unroll
    for (int off = 32; off > 0; off >>= 1) kacc += __shfl_down(kacc, off);
    __shared__ double wsum[4];
    if (l == 0) wsum[w] = kacc;
    __syncthreads();
    if (threadIdx.x == 0)
      atomicAdd(klsum, (wsum[0] + wsum[1]) + (wsum[2] + wsum[3]));
  }
}

// grid (64, 16): x = rowgroup (256 rows), y = split. 4 waves x 64 rows each.
// B staged through 2 x 16 KB LDS buffers (8 tiles/chunk), shared by 4 waves.
__global__ __launch_bounds__(256, 4) void filter_kernel(const _Float16* __restrict__ Ah,
                                                        const _Float16* __restrict__ Bh,
                                                        float* __restrict__ W1) {
  __shared__ _Float16 sB[2][8192];   // 2 x 16 KB
  const int tid = threadIdx.x;
  const int lane = tid & 63;
  const int wave = tid >> 6;
  const int split = blockIdx.y;
  const int rowbase = blockIdx.x * 256 + wave * 64;   // 4 rowtiles of 16
  const int c16 = lane & 15, quad = lane >> 4;
  const unsigned c2 = (unsigned)(lane & 3);           // low 2 bits of c16

  half8 uh0[4], uh1[4];
#pragma unroll
  for (int rt = 0; rt < 4; ++rt) {
    const size_t abase = (size_t)(rowbase + rt * 16 + c16) * 64 + quad * 8;
    uh0[rt] = *(const half8*)(Ah + abase);
    uh1[rt] = *(const half8*)(Ah + abase + 32);
  }

  float a1[4][4];
#pragma unroll
  for (int rt = 0; rt < 4; ++rt)
#pragma unroll
    for (int r = 0; r < 4; ++r) a1[rt][r] = -INFINITY;

  const f32x4 fzero = {0.f, 0.f, 0.f, 0.f};
  const _Float16* gB = Bh + (size_t)split * SPLITK * 64;  // 128 KB region

  // stage chunk 0 (each thread: 4 x 16B, coalesced; linear copy)
  float4 st[4];
#pragma unroll
  for (int j = 0; j < 4; ++j) st[j] = *(const float4*)(gB + j * 2048 + tid * 8);
#pragma unroll
  for (int j = 0; j < 4; ++j) *(float4*)(&sB[0][j * 2048 + tid * 8]) = st[j];
  __syncthreads();

  // swizzled read offsets (halfs): row c16, physical slot = logical ^ (c16&7)
  const int key = c16 & 7;
  const int rs0h = c16 * 64 + (quad ^ key) * 8;         // p-part (slots 0-3)
  const int rs1h = c16 * 64 + (((quad + 4) ^ key)) * 8; // q-part (slots 4-7)

#pragma unroll 1
  for (int ch = 0; ch < 8; ++ch) {
    if (ch < 7) {
      const _Float16* src = gB + (size_t)(ch + 1) * 8192;
#pragma unroll
      for (int j = 0; j < 4; ++j) st[j] = *(const float4*)(src + j * 2048 + tid * 8);
    }
    const _Float16* buf = sB[ch & 1];
#pragma unroll 1
    for (int tp = 0; tp < 4; ++tp) {          // 4 tile-pairs per chunk
      const _Float16* b0 = buf + (2 * tp) * 1024;
      const _Float16* b1 = buf + (2 * tp + 1) * 1024;
      const half8 x0 = *(const half8*)(b0 + rs0h);
      const half8 x1 = *(const half8*)(b0 + rs1h);
      const half8 y0 = *(const half8*)(b1 + rs0h);
      const half8 y1 = *(const half8*)(b1 + rs1h);
      const unsigned ta = (unsigned)((ch * 8 + 2 * tp) << 2) | c2;
      const unsigned tb = ta + 4;               // next tile, same c2
#pragma unroll
      for (int rt = 0; rt < 4; ++rt) {
        f32x4 h0 = __builtin_amdgcn_mfma_f32_16x16x32_f16(uh0[rt], x0, fzero, 0, 0, 0);
        h0 = __builtin_amdgcn_mfma_f32_16x16x32_f16(uh1[rt], x1, h0, 0, 0, 0);
        f32x4 h1 = __builtin_amdgcn_mfma_f32_16x16x32_f16(uh0[rt], y0, fzero, 0, 0, 0);
        h1 = __builtin_amdgcn_mfma_f32_16x16x32_f16(uh1[rt], y1, h1, 0, 0, 0);
#pragma unroll
        for (int r = 0; r < 4; ++r) {
          const float pa = __uint_as_float((__float_as_uint(h0[r]) & PMASK) | ta);
          const float pb = __uint_as_float((__float_as_uint(h1[r]) & PMASK) | tb);
          a1[rt][r] = fmaxf(fmaxf(pa, pb), a1[rt][r]);   // v_max3
        }
      }
    }
    __syncthreads();
    if (ch < 7) {
      _Float16* dst = sB[(ch + 1) & 1];
#pragma unroll
      for (int j = 0; j < 4; ++j) *(float4*)(dst + j * 2048 + tid * 8) = st[j];
    }
    __syncthreads();
  }

  // epilogue: reduce over the 4 columns of each group (lane bits 0,1), then
  // store W1[split][row][group], group = c16>>2 — block-contiguous 4KB runs.
#pragma unroll
  for (int rt = 0; rt < 4; ++rt)
#pragma unroll
    for (int r = 0; r < 4; ++r) {
      float x = a1[rt][r];
      x = fmaxf(x, __shfl_xor(x, 1));
      x = fmaxf(x, __shfl_xor(x, 2));
      if ((lane & 3) == 0) {
        const int row_r = rowbase + rt * 16 + quad * 4 + r;  // C: row=quad*4+reg
        W1[(size_t)split * (NROWS * 4) + row_r * 4 + (c16 >> 2)] = x;
      }
    }
}

// exact fp32 score, p/q broadcast from LDS (identical formula to R2)
__device__ __forceinline__ float exact_score(const float4* __restrict__ cb4,
                                             const float4* __restrict__ spq,
                                             int k) {
  float s0 = 0.0f, s1 = 0.0f, s2 = 0.0f, s3 = 0.0f;
#pragma unroll
  for (int m = 0; m < 8; ++m) {
    const float4 cv = cb4[k * 8 + m];
    const float4 pv = spq[m];        // p[4m..4m+3]
    const float4 qv = spq[8 + m];    // q[4m..4m+3]
    s0 = fmaf(cv.x, fmaf(qv.x, cv.x, pv.x), s0);
    s1 = fmaf(cv.y, fmaf(qv.y, cv.y, pv.y), s1);
    s2 = fmaf(cv.z, fmaf(qv.z, cv.z, pv.z), s2);
    s3 = fmaf(cv.w, fmaf(qv.w, cv.w, pv.w), s3);
  }
  return (s0 + s1) + (s2 + s3);
}

// 1 wave per row; 4 rows per block. lane = (split, group): one W1 value each.
__global__ __launch_bounds__(256, 4) void merge_kernel(const float* __restrict__ PQ,
                                                       const float* __restrict__ cb,
                                                       const float* __restrict__ W1,
                                                       const float* __restrict__ M1,
                                                       const double* __restrict__ klsum,
                                                       int* __restrict__ idx_final,
                                                       float* __restrict__ out1,
                                                       float* __restrict__ out2) {
  __shared__ float4 spq_s[4][16];
  const int lane = threadIdx.x & 63;
  const int wave = threadIdx.x >> 6;
  const int row = blockIdx.x * 4 + wave;
  const int sp = lane >> 2, gr = lane & 3;

  if (lane < 16)
    spq_s[wave][lane] = ((const float4*)(PQ + (size_t)row * 64))[lane];
  __syncthreads();
  const float4* spq = spq_s[wave];
  const float4* __restrict__ cb4 = (const float4*)cb;

  // per-row rigorous bound S = sum |p|M1 + |q|M1^2
  float s = 0.0f;
  if (lane < DIM) {
    const float m1 = M1[lane];
    const float pd = ((const float*)spq)[lane];
    const float qd = ((const float*)spq)[32 + lane];
    s = fabsf(pd) * m1 + fabsf(qd) * m1 * m1;
  }
#pragma unroll
  for (int off = 1; off < 32; off <<= 1) s += __shfl_xor(s, off);
  const float Sn = __shfl(s, 0);

  // one packed group-max per lane
  const float wv = W1[(size_t)sp * (NROWS * 4) + row * 4 + gr];
  float As = wv;
#pragma unroll
  for (int off = 1; off < 64; off <<= 1) As = fmaxf(As, __shfl_xor(As, off));
  const float Btot = 1.05e-3f * Sn + 1e-4f * (fabsf(As) + 1.0f) + 1e-3f;

  // ---- phase A: exact-rescore stored winners of candidate groups ----
  const float TA = As - 2.0f * Btot;
  float best = -INFINITY;
  int bk = 0x7FFFFFFF;
  if (wv >= TA) {
    const unsigned bits = __float_as_uint(wv);
    const int tile = (int)((bits >> 2) & 63u);
    const int cc2 = (int)(bits & 3u);
    const int k = sp * SPLITK + tile * 16 + gr * 4 + cc2;
    best = exact_score(cb4, spq, k);
    bk = k;
  }
#pragma unroll
  for (int off = 1; off < 64; off <<= 1) {
    const float ov = __shfl_xor(best, off);
    const int ok = __shfl_xor(bk, off);
    if (ov > best || (ov == best && ok < bk)) { best = ov; bk = ok; }
  }
  const float Estar = best;   // exact score of some real k; all lanes agree

  // ---- phase B: full rescan of groups that could still contain the max ----
  unsigned long long m = __ballot(wv + Btot >= Estar);
#pragma unroll 1
  while (m) {
    const int e = __builtin_ctzll(m);
    m &= m - 1;
    const int s_ = e >> 2, g_ = e & 3;
#pragma unroll
    for (int j = 0; j < 4; ++j) {             // lane = tile, j = col-in-group
      const int k = s_ * SPLITK + lane * 16 + g_ * 4 + j;
      const float sc = exact_score(cb4, spq, k);
      if (sc > best || (sc == best && k < bk)) { best = sc; bk = k; }
    }
  }
  // final cross-lane argmax, min-k on ties (numpy first-max)
#pragma unroll
  for (int off = 1; off < 64; off <<= 1) {
    const float ov = __shfl_xor(best, off);
    const int ok = __shfl_xor(bk, off);
    if (ov > best || (ov == best && ok < bk)) { best = ov; bk = ok; }
  }
  if (lane == 0) { idx_final[row] = bk; out2[row] = (float)bk; }
  if (blockIdx.x == 0 && threadIdx.x == 0)
    out1[0] = (float)(klsum[0] * (1.4426 * 0.5) / (double)NROWS);
}

// coalesced out0 writes: j -> (t, d, c); n = t*8+c
__global__ __launch_bounds__(256) void gather_kernel(const float* __restrict__ cb,
                                                     const int* __restrict__ idx_final,
                                                     float* __restrict__ out0) {
  const int j = blockIdx.x * 256 + threadIdx.x;  // [0, 524288)
  const int t = j >> 8, r = j & 255;
  const int d = r >> 3, c = r & 7;
  out0[j] = cb[idx_final[t * 8 + c] * DIM + d];
}

extern "C" void kernel_launch(void* const* d_in, const int* in_sizes, int n_in,
                              void* d_out, int out_size, void* d_ws, size_t ws_size,
                              hipStream_t stream) {
  const float* z  = (const float*)d_in[0];
  const float* cb = (const float*)d_in[2];   // d_in[1]=noise unused (STE cancels)

  char* ws = (char*)d_ws;
  float*      M1 = (float*)(ws + WS_M1);
  double* klsum  = (double*)(ws + WS_KL);
  float*      PQ = (float*)(ws + WS_PQ);
  _Float16*   Ah = (_Float16*)(ws + WS_AH);
  _Float16*   Bh = (_Float16*)(ws + WS_BH);
  float*      W1 = (float*)(ws + WS_W1);
  int* idx_final = (int*)(ws + WS_IDX);

  float* out0 = (float*)d_out;            // 524288
  float* out1 = out0 + 524288;            // 1
  float* out2 = out1 + 1;                 // 16384

  (void)hipMemsetAsync(ws, 0, 4096, stream);       // M1, klsum = 0
  prep_kernel<<<1024, 256, 0, stream>>>(cb, z, Bh, M1, PQ, Ah, klsum);
  dim3 fgrid(64, NSPLIT);
  filter_kernel<<<fgrid, 256, 0, stream>>>(Ah, Bh, W1);
  merge_kernel<<<NROWS / 4, 256, 0, stream>>>(PQ, cb, W1, M1, klsum,
                                              idx_final, out1, out2);
  gather_kernel<<<(NTOK * 256) / 256, 256, 0, stream>>>(cb, idx_final, out0);
}

// Round 15
// 165.219 us; speedup vs baseline: 1.3462x; 1.3462x over previous
//
#include <hip/hip_runtime.h>
#include <math.h>

// ---------------------------------------------------------------------------
// GaussianQuant — MFMA-filtered argmax, R15.
// score[n,k] = sum_d p*c + q*c^2;  u=[p,q], v=[c,c^2], score = u.v  (K=64)
// fp16 HI-ONLY approx: |err| <= 1.05e-3*S (rigorous), S = sum |p|M1+|q|M1^2.
// Filter: per (row, GROUP of 4 columns) approx TOP-2: a1 packed with
//   (tile<<2)|c2 in low 8 mantissa bits, a2 value-only.
// Merge (sound): A* = max a1; Btot = 1.05e-3*S + 1e-4*(|A*|+1) + 1e-3.
//   Phase A: exact-rescore stored winners of groups with a1 >= A*-2Btot -> E*.
//   Phase B: full 256-k rescan only of groups with a2 + Btot >= E*.
//   (R14 stored top-1 only, so every row rescanned its winner's group — the
//   106 us merge. With a2, the winner's group no longer auto-flags.)
//   Soundness: if k* (true argmax / first-max tie) is its group's winner,
//   a1[g*] >= E*-Btot >= A*-2Btot -> phase A; else approx(k*) <= a2[g*] ->
//   a2[g*]+Btot >= true(k*) = E*max -> flagged. Min-k ties everywhere.
// ---------------------------------------------------------------------------

typedef _Float16 half8 __attribute__((ext_vector_type(8)));
typedef float f32x4 __attribute__((ext_vector_type(4)));

#define DIM 32
#define NTOK 2048
#define NROWS 16384
#define KSIZE 16384
#define NSPLIT 16
#define SPLITK 1024
#define PMASK 0xFFFFFF00u              // clear low 8 mantissa bits (tile|c2)

// ws layout (bytes); [0,4096) zeroed by memset each launch
#define WS_M1   0                       // 32 float (atomicMax targets)
#define WS_KL   256                     // 1 double (atomicAdd target)
#define WS_PQ   4096                    // 4 MB fp32 [row][64]
#define WS_AH   (WS_PQ + 4194304)       // 2 MB fp16 [row][64]
#define WS_BH   (WS_AH + 2097152)       // 2 MB fp16 [k][64] PRE-SWIZZLED
#define WS_W1   (WS_BH + 2097152)       // 4 MB fp32 [split][row][4] packed a1
#define WS_W2   (WS_W1 + 4194304)       // 4 MB fp32 [split][row][4] a2
#define WS_IDX  (WS_W2 + 4194304)       // 64 KB int

// Fused prep, 1024 blocks: [0,512) pack codebook (swizzled) + per-dim max;
// [512,1024) compute p,q + fp16 pack + KL partial sum.
__global__ __launch_bounds__(256) void prep_kernel(const float* __restrict__ cb,
                                                   const float* __restrict__ z,
                                                   _Float16* __restrict__ Bh,
                                                   float* __restrict__ M1,
                                                   float* __restrict__ PQ,
                                                   _Float16* __restrict__ Ah,
                                                   double* __restrict__ klsum) {
  const int w = threadIdx.x >> 6, l = threadIdx.x & 63;
  const int sub = l >> 5, d = l & 31;
  if (blockIdx.x < 512) {
    __shared__ float lm[8][DIM];
    float m = 0.0f;
#pragma unroll
    for (int i = 0; i < 4; ++i) {
      const int k = blockIdx.x * 32 + i * 8 + w * 2 + sub;
      const float c = cb[k * DIM + d];
      // swizzled slot layout: logical slot s (8 halfs) stored at s ^ (k&7)
      const int key = k & 7;
      const int sc = (d >> 3) ^ key;          // c-part: logical slot d>>3
      const int sq = (4 + (d >> 3)) ^ key;    // c^2-part: logical slot 4+d>>3
      Bh[(size_t)k * 64 + sc * 8 + (d & 7)] = (_Float16)c;
      Bh[(size_t)k * 64 + sq * 8 + (d & 7)] = (_Float16)(c * c);
      m = fmaxf(m, fabsf(c));
    }
    lm[threadIdx.x >> 5][d] = m;
    __syncthreads();
    if (threadIdx.x < DIM) {
      float x = lm[0][threadIdx.x];
#pragma unroll
      for (int i = 1; i < 8; ++i) x = fmaxf(x, lm[i][threadIdx.x]);
      atomicMax((unsigned*)&M1[threadIdx.x], __float_as_uint(x));
    }
  } else {
    const int blk = blockIdx.x - 512;
    double kacc = 0.0;
#pragma unroll 1
    for (int i = 0; i < 4; ++i) {
      const int row = blk * 32 + i * 8 + w * 2 + sub;
      const int t = row >> 3, c = row & 7;
      const float mu = z[t * 512 + d * 8 + c];
      float lv = z[t * 512 + 256 + d * 8 + c];
      lv = fminf(fmaxf(lv, -30.0f), 20.0f);
      const float stdv = expf(0.5f * lv);
      const float iv = 1.0f / (stdv * stdv);   // identical to R2 expression
      const float p = mu * iv;
      const float q = 0.5f * (1.0f - iv);
      PQ[(size_t)row * 64 + d] = p;
      PQ[(size_t)row * 64 + 32 + d] = q;
      Ah[(size_t)row * 64 + d] = (_Float16)p;
      Ah[(size_t)row * 64 + 32 + d] = (_Float16)q;
      kacc += (double)(mu * mu + stdv * stdv - 1.0f - lv);
    }
#pragma unroll
    for (int off = 32; off > 0; off >>= 1) kacc += __shfl_down(kacc, off);
    __shared__ double wsum[4];
    if (l == 0) wsum[w] = kacc;
    __syncthreads();
    if (threadIdx.x == 0)
      atomicAdd(klsum, (wsum[0] + wsum[1]) + (wsum[2] + wsum[3]));
  }
}

// grid (64, 16): x = rowgroup (256 rows), y = split. 4 waves x 64 rows each.
// B staged through 2 x 16 KB LDS buffers (8 tiles/chunk), shared by 4 waves.
__global__ __launch_bounds__(256, 4) void filter_kernel(const _Float16* __restrict__ Ah,
                                                        const _Float16* __restrict__ Bh,
                                                        float* __restrict__ W1,
                                                        float* __restrict__ W2) {
  __shared__ _Float16 sB[2][8192];   // 2 x 16 KB
  const int tid = threadIdx.x;
  const int lane = tid & 63;
  const int wave = tid >> 6;
  const int split = blockIdx.y;
  const int rowbase = blockIdx.x * 256 + wave * 64;   // 4 rowtiles of 16
  const int c16 = lane & 15, quad = lane >> 4;
  const unsigned c2 = (unsigned)(lane & 3);           // low 2 bits of c16

  half8 uh0[4], uh1[4];
#pragma unroll
  for (int rt = 0; rt < 4; ++rt) {
    const size_t abase = (size_t)(rowbase + rt * 16 + c16) * 64 + quad * 8;
    uh0[rt] = *(const half8*)(Ah + abase);
    uh1[rt] = *(const half8*)(Ah + abase + 32);
  }

  float a1[4][4], a2[4][4];
#pragma unroll
  for (int rt = 0; rt < 4; ++rt)
#pragma unroll
    for (int r = 0; r < 4; ++r) { a1[rt][r] = -INFINITY; a2[rt][r] = -INFINITY; }

  const f32x4 fzero = {0.f, 0.f, 0.f, 0.f};
  const _Float16* gB = Bh + (size_t)split * SPLITK * 64;  // 128 KB region

  // stage chunk 0 (each thread: 4 x 16B, coalesced; linear copy)
  float4 st[4];
#pragma unroll
  for (int j = 0; j < 4; ++j) st[j] = *(const float4*)(gB + j * 2048 + tid * 8);
#pragma unroll
  for (int j = 0; j < 4; ++j) *(float4*)(&sB[0][j * 2048 + tid * 8]) = st[j];
  __syncthreads();

  // swizzled read offsets (halfs): row c16, physical slot = logical ^ (c16&7)
  const int key = c16 & 7;
  const int rs0h = c16 * 64 + (quad ^ key) * 8;         // p-part (slots 0-3)
  const int rs1h = c16 * 64 + (((quad + 4) ^ key)) * 8; // q-part (slots 4-7)

#pragma unroll 1
  for (int ch = 0; ch < 8; ++ch) {
    if (ch < 7) {
      const _Float16* src = gB + (size_t)(ch + 1) * 8192;
#pragma unroll
      for (int j = 0; j < 4; ++j) st[j] = *(const float4*)(src + j * 2048 + tid * 8);
    }
    const _Float16* buf = sB[ch & 1];
#pragma unroll 1
    for (int tp = 0; tp < 4; ++tp) {          // 4 tile-pairs per chunk
      const _Float16* b0 = buf + (2 * tp) * 1024;
      const _Float16* b1 = buf + (2 * tp + 1) * 1024;
      const half8 x0 = *(const half8*)(b0 + rs0h);
      const half8 x1 = *(const half8*)(b0 + rs1h);
      const half8 y0 = *(const half8*)(b1 + rs0h);
      const half8 y1 = *(const half8*)(b1 + rs1h);
      const unsigned ta = (unsigned)((ch * 8 + 2 * tp) << 2) | c2;
      const unsigned tb = ta + 4;               // next tile, same c2
#pragma unroll
      for (int rt = 0; rt < 4; ++rt) {
        f32x4 h0 = __builtin_amdgcn_mfma_f32_16x16x32_f16(uh0[rt], x0, fzero, 0, 0, 0);
        h0 = __builtin_amdgcn_mfma_f32_16x16x32_f16(uh1[rt], x1, h0, 0, 0, 0);
        f32x4 h1 = __builtin_amdgcn_mfma_f32_16x16x32_f16(uh0[rt], y0, fzero, 0, 0, 0);
        h1 = __builtin_amdgcn_mfma_f32_16x16x32_f16(uh1[rt], y1, h1, 0, 0, 0);
#pragma unroll
        for (int r = 0; r < 4; ++r) {
          const float pa = __uint_as_float((__float_as_uint(h0[r]) & PMASK) | ta);
          const float pb = __uint_as_float((__float_as_uint(h1[r]) & PMASK) | tb);
          const float hi = fmaxf(pa, pb);
          const float lo = fminf(pa, pb);
          // exact top-2 update: new a2 = max3(a2, lo, min(hi, old a1))
          a2[rt][r] = fmaxf(fmaxf(a2[rt][r], lo), fminf(hi, a1[rt][r]));
          a1[rt][r] = fmaxf(a1[rt][r], hi);
        }
      }
    }
    __syncthreads();
    if (ch < 7) {
      _Float16* dst = sB[(ch + 1) & 1];
#pragma unroll
      for (int j = 0; j < 4; ++j) *(float4*)(dst + j * 2048 + tid * 8) = st[j];
    }
    __syncthreads();
  }

  // epilogue: top-2 reduce over the 4 columns of each group (lane bits 0,1),
  // then store [split][row][group] — block-contiguous 4KB runs.
#pragma unroll
  for (int rt = 0; rt < 4; ++rt)
#pragma unroll
    for (int r = 0; r < 4; ++r) {
      float x1 = a1[rt][r], x2 = a2[rt][r];
#pragma unroll
      for (int off = 1; off < 4; off <<= 1) {
        const float y1 = __shfl_xor(x1, off);
        const float y2 = __shfl_xor(x2, off);
        x2 = fmaxf(fmaxf(x2, y2), fminf(x1, y1));
        x1 = fmaxf(x1, y1);
      }
      if ((lane & 3) == 0) {
        const int row_r = rowbase + rt * 16 + quad * 4 + r;  // C: row=quad*4+reg
        W1[(size_t)split * (NROWS * 4) + row_r * 4 + (c16 >> 2)] = x1;
        W2[(size_t)split * (NROWS * 4) + row_r * 4 + (c16 >> 2)] = x2;
      }
    }
}

// exact fp32 score, p/q broadcast from LDS (identical formula to R2)
__device__ __forceinline__ float exact_score(const float4* __restrict__ cb4,
                                             const float4* __restrict__ spq,
                                             int k) {
  float s0 = 0.0f, s1 = 0.0f, s2 = 0.0f, s3 = 0.0f;
#pragma unroll
  for (int m = 0; m < 8; ++m) {
    const float4 cv = cb4[k * 8 + m];
    const float4 pv = spq[m];        // p[4m..4m+3]
    const float4 qv = spq[8 + m];    // q[4m..4m+3]
    s0 = fmaf(cv.x, fmaf(qv.x, cv.x, pv.x), s0);
    s1 = fmaf(cv.y, fmaf(qv.y, cv.y, pv.y), s1);
    s2 = fmaf(cv.z, fmaf(qv.z, cv.z, pv.z), s2);
    s3 = fmaf(cv.w, fmaf(qv.w, cv.w, pv.w), s3);
  }
  return (s0 + s1) + (s2 + s3);
}

// 1 wave per row; 4 rows per block. lane = (split, group).
__global__ __launch_bounds__(256, 4) void merge_kernel(const float* __restrict__ PQ,
                                                       const float* __restrict__ cb,
                                                       const float* __restrict__ W1,
                                                       const float* __restrict__ W2,
                                                       const float* __restrict__ M1,
                                                       const double* __restrict__ klsum,
                                                       int* __restrict__ idx_final,
                                                       float* __restrict__ out1,
                                                       float* __restrict__ out2) {
  __shared__ float4 spq_s[4][16];
  const int lane = threadIdx.x & 63;
  const int wave = threadIdx.x >> 6;
  const int row = blockIdx.x * 4 + wave;
  const int sp = lane >> 2, gr = lane & 3;

  if (lane < 16)
    spq_s[wave][lane] = ((const float4*)(PQ + (size_t)row * 64))[lane];
  __syncthreads();
  const float4* spq = spq_s[wave];
  const float4* __restrict__ cb4 = (const float4*)cb;

  // per-row rigorous bound S = sum |p|M1 + |q|M1^2
  float s = 0.0f;
  if (lane < DIM) {
    const float m1 = M1[lane];
    const float pd = ((const float*)spq)[lane];
    const float qd = ((const float*)spq)[32 + lane];
    s = fabsf(pd) * m1 + fabsf(qd) * m1 * m1;
  }
#pragma unroll
  for (int off = 1; off < 32; off <<= 1) s += __shfl_xor(s, off);
  const float Sn = __shfl(s, 0);

  // one packed group top-1 + one group top-2 per lane
  const float wv1 = W1[(size_t)sp * (NROWS * 4) + row * 4 + gr];
  const float wv2 = W2[(size_t)sp * (NROWS * 4) + row * 4 + gr];
  float As = wv1;
#pragma unroll
  for (int off = 1; off < 64; off <<= 1) As = fmaxf(As, __shfl_xor(As, off));
  const float Btot = 1.05e-3f * Sn + 1e-4f * (fabsf(As) + 1.0f) + 1e-3f;

  // ---- phase A: exact-rescore stored winners of candidate groups ----
  const float TA = As - 2.0f * Btot;
  float best = -INFINITY;
  int bk = 0x7FFFFFFF;
  if (wv1 >= TA) {
    const unsigned bits = __float_as_uint(wv1);
    const int tile = (int)((bits >> 2) & 63u);
    const int cc2 = (int)(bits & 3u);
    const int k = sp * SPLITK + tile * 16 + gr * 4 + cc2;
    best = exact_score(cb4, spq, k);
    bk = k;
  }
#pragma unroll
  for (int off = 1; off < 64; off <<= 1) {
    const float ov = __shfl_xor(best, off);
    const int ok = __shfl_xor(bk, off);
    if (ov > best || (ov == best && ok < bk)) { best = ov; bk = ok; }
  }
  const float Estar = best;   // exact score of some real k; all lanes agree

  // ---- phase B: rescan only groups whose RUNNER-UP could matter ----
  unsigned long long m = __ballot(wv2 + Btot >= Estar);
#pragma unroll 1
  while (m) {
    const int e = __builtin_ctzll(m);
    m &= m - 1;
    const int s_ = e >> 2, g_ = e & 3;
#pragma unroll
    for (int j = 0; j < 4; ++j) {             // lane = tile, j = col-in-group
      const int k = s_ * SPLITK + lane * 16 + g_ * 4 + j;
      const float sc = exact_score(cb4, spq, k);
      if (sc > best || (sc == best && k < bk)) { best = sc; bk = k; }
    }
  }
  // final cross-lane argmax, min-k on ties (numpy first-max)
#pragma unroll
  for (int off = 1; off < 64; off <<= 1) {
    const float ov = __shfl_xor(best, off);
    const int ok = __shfl_xor(bk, off);
    if (ov > best || (ov == best && ok < bk)) { best = ov; bk = ok; }
  }
  if (lane == 0) { idx_final[row] = bk; out2[row] = (float)bk; }
  if (blockIdx.x == 0 && threadIdx.x == 0)
    out1[0] = (float)(klsum[0] * (1.4426 * 0.5) / (double)NROWS);
}

// coalesced out0 writes: j -> (t, d, c); n = t*8+c
__global__ __launch_bounds__(256) void gather_kernel(const float* __restrict__ cb,
                                                     const int* __restrict__ idx_final,
                                                     float* __restrict__ out0) {
  const int j = blockIdx.x * 256 + threadIdx.x;  // [0, 524288)
  const int t = j >> 8, r = j & 255;
  const int d = r >> 3, c = r & 7;
  out0[j] = cb[idx_final[t * 8 + c] * DIM + d];
}

extern "C" void kernel_launch(void* const* d_in, const int* in_sizes, int n_in,
                              void* d_out, int out_size, void* d_ws, size_t ws_size,
                              hipStream_t stream) {
  const float* z  = (const float*)d_in[0];
  const float* cb = (const float*)d_in[2];   // d_in[1]=noise unused (STE cancels)

  char* ws = (char*)d_ws;
  float*      M1 = (float*)(ws + WS_M1);
  double* klsum  = (double*)(ws + WS_KL);
  float*      PQ = (float*)(ws + WS_PQ);
  _Float16*   Ah = (_Float16*)(ws + WS_AH);
  _Float16*   Bh = (_Float16*)(ws + WS_BH);
  float*      W1 = (float*)(ws + WS_W1);
  float*      W2 = (float*)(ws + WS_W2);
  int* idx_final = (int*)(ws + WS_IDX);

  float* out0 = (float*)d_out;            // 524288
  float* out1 = out0 + 524288;            // 1
  float* out2 = out1 + 1;                 // 16384

  (void)hipMemsetAsync(ws, 0, 4096, stream);       // M1, klsum = 0
  prep_kernel<<<1024, 256, 0, stream>>>(cb, z, Bh, M1, PQ, Ah, klsum);
  dim3 fgrid(64, NSPLIT);
  filter_kernel<<<fgrid, 256, 0, stream>>>(Ah, Bh, W1, W2);
  merge_kernel<<<NROWS / 4, 256, 0, stream>>>(PQ, cb, W1, W2, M1, klsum,
                                              idx_final, out1, out2);
  gather_kernel<<<(NTOK * 256) / 256, 256, 0, stream>>>(cb, idx_final, out0);
}